// Round 2
// baseline (832.299 us; speedup 1.0000x reference)
//
#include <hip/hip_runtime.h>
#include <stdint.h>

typedef unsigned short u16;
typedef __attribute__((ext_vector_type(4))) float f32x4;
typedef __attribute__((ext_vector_type(8))) __bf16 bf16x8;
typedef __attribute__((address_space(3))) void lds_void;
typedef const __attribute__((address_space(1))) void gbl_void;

__device__ __forceinline__ u16 f2bf(float f) {
    uint32_t u = __float_as_uint(f);
    u += 0x7FFFu + ((u >> 16) & 1u);
    return (u16)(u >> 16);
}

// ---------------- x f32 -> bf16 ----------------
__global__ __launch_bounds__(256) void cvt_bf16_kernel(const float* __restrict__ in,
                                                       u16* __restrict__ out, int n4) {
    int i = blockIdx.x * 256 + threadIdx.x;
    if (i >= n4) return;
    float4 v = reinterpret_cast<const float4*>(in)[i];
    ushort4 o;
    o.x = f2bf(v.x); o.y = f2bf(v.y); o.z = f2bf(v.z); o.w = f2bf(v.w);
    reinterpret_cast<ushort4*>(out)[i] = o;
}

// ---------------- W [K][N] f32 -> Wt [N][K] bf16 (2048x2048) ----------------
__global__ __launch_bounds__(256) void transpose_w_kernel(const float* __restrict__ W,
                                                          u16* __restrict__ Wt) {
    __shared__ float tile[32][33];
    const int bx = blockIdx.x, by = blockIdx.y;
    const int tx = threadIdx.x;  // 0..31
    const int ty = threadIdx.y;  // 0..7
#pragma unroll
    for (int i = 0; i < 4; i++)
        tile[ty + i * 8][tx] = W[(size_t)(by * 32 + ty + i * 8) * 2048 + bx * 32 + tx];
    __syncthreads();
#pragma unroll
    for (int i = 0; i < 4; i++)
        Wt[(size_t)(bx * 32 + ty + i * 8) * 2048 + by * 32 + tx] = f2bf(tile[tx][ty + i * 8]);
}

// ---------------- GEMM: C[M][N] = A[M][K] * Bt[N][K]^T  (bf16 in) ----------------
// 128x128 tile, 4 waves (2x2), BK=32, 16x16x32 bf16 MFMA, global_load_lds staging.
template <bool F32OUT>
__global__ __launch_bounds__(256) void gemm_bt_kernel(const u16* __restrict__ A,
                                                      const u16* __restrict__ Bt,
                                                      void* __restrict__ Cout,
                                                      const float* __restrict__ bias,
                                                      int M, int N, int K) {
    __shared__ u16 As[128 * 32];
    __shared__ u16 Bs[128 * 32];
    const int tid = threadIdx.x;
    const int lane = tid & 63, wave = tid >> 6;
    const int l15 = lane & 15, l4 = lane >> 4;
    const int wm = wave >> 1, wn = wave & 1;
    const int bm = blockIdx.x, bn = blockIdx.y;

    f32x4 acc[4][4] = {};

    const int r0 = tid >> 2;             // rows 0..63
    const int r1 = r0 + 64;              // rows 64..127
    const int c0 = (tid & 3) * 8;        // element offset within 32-wide K chunk
    const u16* ga0 = A + (size_t)(bm * 128 + r0) * K + c0;
    const u16* ga1 = A + (size_t)(bm * 128 + r1) * K + c0;
    const u16* gb0 = Bt + (size_t)(bn * 128 + r0) * K + c0;
    const u16* gb1 = Bt + (size_t)(bn * 128 + r1) * K + c0;
    const int ldsoff = wave * 1024;  // bytes

    for (int kb = 0; kb < K; kb += 32) {
        __builtin_amdgcn_global_load_lds((gbl_void*)(ga0 + kb),
                                         (lds_void*)((char*)As + ldsoff), 16, 0, 0);
        __builtin_amdgcn_global_load_lds((gbl_void*)(ga1 + kb),
                                         (lds_void*)((char*)As + 4096 + ldsoff), 16, 0, 0);
        __builtin_amdgcn_global_load_lds((gbl_void*)(gb0 + kb),
                                         (lds_void*)((char*)Bs + ldsoff), 16, 0, 0);
        __builtin_amdgcn_global_load_lds((gbl_void*)(gb1 + kb),
                                         (lds_void*)((char*)Bs + 4096 + ldsoff), 16, 0, 0);
        __syncthreads();

        bf16x8 af[4], bfr[4];
#pragma unroll
        for (int m = 0; m < 4; ++m)
            af[m] = *reinterpret_cast<const bf16x8*>(&As[(wm * 64 + m * 16 + l15) * 32 + l4 * 8]);
#pragma unroll
        for (int n = 0; n < 4; ++n)
            bfr[n] = *reinterpret_cast<const bf16x8*>(&Bs[(wn * 64 + n * 16 + l15) * 32 + l4 * 8]);
#pragma unroll
        for (int m = 0; m < 4; ++m)
#pragma unroll
            for (int n = 0; n < 4; ++n)
                acc[m][n] = __builtin_amdgcn_mfma_f32_16x16x32_bf16(af[m], bfr[n], acc[m][n], 0, 0, 0);
        __syncthreads();
    }

    const int rbase = bm * 128 + wm * 64;
    const int cbase = bn * 128 + wn * 64;
#pragma unroll
    for (int m = 0; m < 4; ++m) {
#pragma unroll
        for (int n = 0; n < 4; ++n) {
            const int c = cbase + n * 16 + l15;
#pragma unroll
            for (int j = 0; j < 4; ++j) {
                const int r = rbase + m * 16 + l4 * 4 + j;
                if (F32OUT)
                    ((float*)Cout)[(size_t)r * N + c] = acc[m][n][j] + bias[c];
                else
                    ((u16*)Cout)[(size_t)r * N + c] = f2bf(acc[m][n][j]);
            }
        }
    }
}

// ---------------- causal flash attention ----------------
// grid: (S/64, B*H). block: 256 (4 waves x 16 q-rows). KV tiles of 64.
// qkv: [B*S][6144] bf16 (q | k | v each 2048 cols, head-major 16x128).
// ctx: [B*S][2048] bf16.
#define KSTR 136  // K-tile LDS stride: 128 dh + 8 pad (272B = 17*16B, uint4-aligned)
__global__ __launch_bounds__(256) void attn_kernel(const u16* __restrict__ qkv,
                                                   u16* __restrict__ ctx) {
    __shared__ u16 Ks[64 * KSTR]; // [kv][dh] padded (stride 136 for 128 dh elems)
    __shared__ u16 Vt[128 * 72];  // [dh][kv] padded, kv XOR-swizzled by ((dh>>3)&3)<<3
    __shared__ u16 Ps[4 * 16 * 72];// per-wave [q][kv] padded
    const int tid = threadIdx.x, lane = tid & 63, w = tid >> 6;
    const int l15 = lane & 15, l4 = lane >> 4;
    const int qt = blockIdx.x;   // 0..31
    const int bh = blockIdx.y;   // 0..63
    const int b = bh >> 4, h = bh & 15;
    const int qb = qt * 64;

    // Q fragments in registers: rows w*16 + l15, dh = kk*32 + l4*8 .. +7
    bf16x8 qf[4];
    {
        const size_t rowQ = (size_t)(b * 2048 + qb + w * 16 + l15) * 6144 + h * 128;
#pragma unroll
        for (int kk = 0; kk < 4; kk++)
            qf[kk] = *reinterpret_cast<const bf16x8*>(&qkv[rowQ + kk * 32 + l4 * 8]);
    }

    float m_r[4], l_r[4];
    f32x4 o[8] = {};
#pragma unroll
    for (int j = 0; j < 4; ++j) { m_r[j] = -1e30f; l_r[j] = 0.f; }

    for (int kt = 0; kt <= qt; ++kt) {
        const int kvb = kt * 64;
        // ---- stage K row-major, V transposed(+swizzled) ----
#pragma unroll
        for (int it = 0; it < 4; ++it) {
            int idx = it * 256 + tid;        // 0..1023
            int kvr = idx >> 4;              // 0..63
            int ch = idx & 15;               // 16B chunk (8 elems)
            const size_t grow = (size_t)(b * 2048 + kvb + kvr) * 6144 + h * 128 + ch * 8;
            *reinterpret_cast<uint4*>(&Ks[kvr * KSTR + ch * 8]) =
                *reinterpret_cast<const uint4*>(&qkv[2048 + grow]);
            uint4 vv = *reinterpret_cast<const uint4*>(&qkv[4096 + grow]);
            const u16* ve = reinterpret_cast<const u16*>(&vv);
            const int kvs = kvr ^ ((ch & 3) << 3);
#pragma unroll
            for (int e = 0; e < 8; ++e)
                Vt[(ch * 8 + e) * 72 + kvs] = ve[e];
        }
        __syncthreads();

        // ---- scores: S[16q][64kv] per wave ----
        f32x4 s[4] = {};
#pragma unroll
        for (int cb = 0; cb < 4; ++cb)
#pragma unroll
            for (int kk = 0; kk < 4; ++kk) {
                bf16x8 kf = *reinterpret_cast<const bf16x8*>(
                    &Ks[(cb * 16 + l15) * KSTR + kk * 32 + l4 * 8]);
                s[cb] = __builtin_amdgcn_mfma_f32_16x16x32_bf16(qf[kk], kf, s[cb], 0, 0, 0);
            }
        const float sc = 0.08838834764831845f;  // 1/sqrt(128)
#pragma unroll
        for (int cb = 0; cb < 4; ++cb) s[cb] *= sc;

        if (kt == qt) {  // diagonal mask: col > row -> -inf
#pragma unroll
            for (int cb = 0; cb < 4; ++cb)
#pragma unroll
                for (int j = 0; j < 4; ++j) {
                    int lr = w * 16 + l4 * 4 + j, lc = cb * 16 + l15;
                    if (lc > lr) s[cb][j] = -1e30f;
                }
        }

        // ---- online softmax (per q-row j, reduce across 16 lanes) ----
#pragma unroll
        for (int j = 0; j < 4; ++j) {
            float tm = fmaxf(fmaxf(s[0][j], s[1][j]), fmaxf(s[2][j], s[3][j]));
#pragma unroll
            for (int msk = 1; msk < 16; msk <<= 1)
                tm = fmaxf(tm, __shfl_xor(tm, msk, 64));
            float mnew = fmaxf(m_r[j], tm);
            float alpha = __expf(m_r[j] - mnew);
            m_r[j] = mnew;
            float rs = 0.f;
#pragma unroll
            for (int cb = 0; cb < 4; ++cb) {
                float p = __expf(s[cb][j] - mnew);
                s[cb][j] = p;
                rs += p;
            }
#pragma unroll
            for (int msk = 1; msk < 16; msk <<= 1)
                rs += __shfl_xor(rs, msk, 64);
            l_r[j] = l_r[j] * alpha + rs;
#pragma unroll
            for (int d = 0; d < 8; ++d) o[d][j] *= alpha;
        }

        // ---- P -> LDS (bf16) ----
#pragma unroll
        for (int cb = 0; cb < 4; ++cb)
#pragma unroll
            for (int j = 0; j < 4; ++j)
                Ps[w * 1152 + (l4 * 4 + j) * 72 + cb * 16 + l15] = f2bf(s[cb][j]);
        __syncthreads();

        // ---- PV: O += P @ V ----
#pragma unroll
        for (int ks = 0; ks < 2; ++ks) {
            bf16x8 pf = *reinterpret_cast<const bf16x8*>(
                &Ps[w * 1152 + l15 * 72 + ks * 32 + l4 * 8]);
#pragma unroll
            for (int d = 0; d < 8; ++d) {
                const int dhrow = d * 16 + l15;
                const int sv = (dhrow >> 3) & 3;
                bf16x8 vf = *reinterpret_cast<const bf16x8*>(
                    &Vt[dhrow * 72 + ks * 32 + ((l4 ^ sv) & 3) * 8]);
                o[d] = __builtin_amdgcn_mfma_f32_16x16x32_bf16(pf, vf, o[d], 0, 0, 0);
            }
        }
        __syncthreads();
    }

    // ---- epilogue: normalize, write ctx bf16 ----
#pragma unroll
    for (int j = 0; j < 4; ++j) {
        float inv = 1.0f / l_r[j];
        size_t row = (size_t)(b * 2048 + qb + w * 16 + l4 * 4 + j) * 2048 + h * 128;
#pragma unroll
        for (int d = 0; d < 8; ++d)
            ctx[row + d * 16 + l15] = f2bf(o[d][j] * inv);
    }
}

extern "C" void kernel_launch(void* const* d_in, const int* in_sizes, int n_in,
                              void* d_out, int out_size, void* d_ws, size_t ws_size,
                              hipStream_t stream) {
    const float* x  = (const float*)d_in[0];
    const float* Wq = (const float*)d_in[1];
    const float* Wk = (const float*)d_in[2];
    const float* Wv = (const float*)d_in[3];
    const float* Wo = (const float*)d_in[4];
    const float* bo = (const float*)d_in[5];
    float* out = (float*)d_out;

    char* ws = (char*)d_ws;
    u16* xb  = (u16*)(ws);                                  // 8192*2048 bf16 (33.5MB) ; reused as ctx
    u16* wtq = (u16*)(ws + 33554432);                       // 6144*2048 bf16 (25.2MB)
    u16* wto = (u16*)(ws + 33554432 + 25165824);            // 2048*2048 bf16 (8.4MB)
    u16* qkv = (u16*)(ws + 67108864);                       // 8192*6144 bf16 (100.7MB)
    u16* ctxb = xb;

    cvt_bf16_kernel<<<16384, 256, 0, stream>>>(x, xb, 4194304);
    dim3 tb(32, 8), tg(64, 64);
    transpose_w_kernel<<<tg, tb, 0, stream>>>(Wq, wtq);
    transpose_w_kernel<<<tg, tb, 0, stream>>>(Wk, wtq + 2048 * 2048);
    transpose_w_kernel<<<tg, tb, 0, stream>>>(Wv, wtq + 2 * 2048 * 2048);
    transpose_w_kernel<<<tg, tb, 0, stream>>>(Wo, wto);

    gemm_bt_kernel<false><<<dim3(64, 48), 256, 0, stream>>>(xb, wtq, qkv, nullptr, 8192, 6144, 2048);
    attn_kernel<<<dim3(32, 64), 256, 0, stream>>>(qkv, ctxb);
    gemm_bt_kernel<true><<<dim3(64, 16), 256, 0, stream>>>(ctxb, wto, out, bo, 8192, 2048, 2048);
}

// Round 3
// 600.727 us; speedup vs baseline: 1.3855x; 1.3855x over previous
//
#include <hip/hip_runtime.h>
#include <stdint.h>

typedef unsigned short u16;
typedef __attribute__((ext_vector_type(4))) float f32x4;
typedef __attribute__((ext_vector_type(8))) __bf16 bf16x8;
typedef __attribute__((address_space(3))) void lds_void;
typedef const __attribute__((address_space(1))) void gbl_void;

__device__ __forceinline__ u16 f2bf(float f) {
    uint32_t u = __float_as_uint(f);
    u += 0x7FFFu + ((u >> 16) & 1u);
    return (u16)(u >> 16);
}

// ---------------- x f32 -> bf16 ----------------
__global__ __launch_bounds__(256) void cvt_bf16_kernel(const float* __restrict__ in,
                                                       u16* __restrict__ out, int n4) {
    int i = blockIdx.x * 256 + threadIdx.x;
    if (i >= n4) return;
    float4 v = reinterpret_cast<const float4*>(in)[i];
    ushort4 o;
    o.x = f2bf(v.x); o.y = f2bf(v.y); o.z = f2bf(v.z); o.w = f2bf(v.w);
    reinterpret_cast<ushort4*>(out)[i] = o;
}

// ---------------- W [K][N] f32 -> Wt [N][K] bf16 (2048x2048) ----------------
__global__ __launch_bounds__(256) void transpose_w_kernel(const float* __restrict__ W,
                                                          u16* __restrict__ Wt) {
    __shared__ float tile[32][33];
    const int bx = blockIdx.x, by = blockIdx.y;
    const int tx = threadIdx.x;  // 0..31
    const int ty = threadIdx.y;  // 0..7
#pragma unroll
    for (int i = 0; i < 4; i++)
        tile[ty + i * 8][tx] = W[(size_t)(by * 32 + ty + i * 8) * 2048 + bx * 32 + tx];
    __syncthreads();
#pragma unroll
    for (int i = 0; i < 4; i++)
        Wt[(size_t)(bx * 32 + ty + i * 8) * 2048 + by * 32 + tx] = f2bf(tile[tx][ty + i * 8]);
}

// ---------------- GEMM: C[M][N] = A[M][K] * Bt[N][K]^T  (bf16 in) ----------------
template <bool F32OUT>
__global__ __launch_bounds__(256) void gemm_bt_kernel(const u16* __restrict__ A,
                                                      const u16* __restrict__ Bt,
                                                      void* __restrict__ Cout,
                                                      const float* __restrict__ bias,
                                                      int M, int N, int K) {
    __shared__ u16 As[128 * 32];
    __shared__ u16 Bs[128 * 32];
    const int tid = threadIdx.x;
    const int lane = tid & 63, wave = tid >> 6;
    const int l15 = lane & 15, l4 = lane >> 4;
    const int wm = wave >> 1, wn = wave & 1;
    const int bm = blockIdx.x, bn = blockIdx.y;

    f32x4 acc[4][4] = {};

    const int r0 = tid >> 2;
    const int r1 = r0 + 64;
    const int c0 = (tid & 3) * 8;
    const u16* ga0 = A + (size_t)(bm * 128 + r0) * K + c0;
    const u16* ga1 = A + (size_t)(bm * 128 + r1) * K + c0;
    const u16* gb0 = Bt + (size_t)(bn * 128 + r0) * K + c0;
    const u16* gb1 = Bt + (size_t)(bn * 128 + r1) * K + c0;
    const int ldsoff = wave * 1024;

    for (int kb = 0; kb < K; kb += 32) {
        __builtin_amdgcn_global_load_lds((gbl_void*)(ga0 + kb),
                                         (lds_void*)((char*)As + ldsoff), 16, 0, 0);
        __builtin_amdgcn_global_load_lds((gbl_void*)(ga1 + kb),
                                         (lds_void*)((char*)As + 4096 + ldsoff), 16, 0, 0);
        __builtin_amdgcn_global_load_lds((gbl_void*)(gb0 + kb),
                                         (lds_void*)((char*)Bs + ldsoff), 16, 0, 0);
        __builtin_amdgcn_global_load_lds((gbl_void*)(gb1 + kb),
                                         (lds_void*)((char*)Bs + 4096 + ldsoff), 16, 0, 0);
        __syncthreads();

        bf16x8 af[4], bfr[4];
#pragma unroll
        for (int m = 0; m < 4; ++m)
            af[m] = *reinterpret_cast<const bf16x8*>(&As[(wm * 64 + m * 16 + l15) * 32 + l4 * 8]);
#pragma unroll
        for (int n = 0; n < 4; ++n)
            bfr[n] = *reinterpret_cast<const bf16x8*>(&Bs[(wn * 64 + n * 16 + l15) * 32 + l4 * 8]);
#pragma unroll
        for (int m = 0; m < 4; ++m)
#pragma unroll
            for (int n = 0; n < 4; ++n)
                acc[m][n] = __builtin_amdgcn_mfma_f32_16x16x32_bf16(af[m], bfr[n], acc[m][n], 0, 0, 0);
        __syncthreads();
    }

    const int rbase = bm * 128 + wm * 64;
    const int cbase = bn * 128 + wn * 64;
#pragma unroll
    for (int m = 0; m < 4; ++m) {
#pragma unroll
        for (int n = 0; n < 4; ++n) {
            const int c = cbase + n * 16 + l15;
#pragma unroll
            for (int j = 0; j < 4; ++j) {
                const int r = rbase + m * 16 + l4 * 4 + j;
                if (F32OUT)
                    ((float*)Cout)[(size_t)r * N + c] = acc[m][n][j] + bias[c];
                else
                    ((u16*)Cout)[(size_t)r * N + c] = f2bf(acc[m][n][j]);
            }
        }
    }
}

// ---------------- causal flash attention ----------------
// grid: 2048 1-D, heavy-first: qt = 31 - flat/64, bh = flat%64.
// qk: [B*S][4096] bf16 (q | k, head-major 16x128). vt: [2048=h*128+dh][8192=b*2048+s].
// ctx: [B*S][2048] bf16.
// LDS tiles linear (global_load_lds), source pre-swizzled; reads apply same XOR.
__global__ __launch_bounds__(256) void attn_kernel(const u16* __restrict__ qk,
                                                   const u16* __restrict__ vt,
                                                   u16* __restrict__ ctx) {
    __shared__ u16 Ks[64 * 128];     // [kv][dh], 16B chunk c stored at c ^ (kv&15)
    __shared__ u16 Vs[128 * 64];     // [dh][kv], 16B chunk c stored at c ^ (dh&7)
    __shared__ u16 Ps[4 * 16 * 64];  // per-wave [q][kv], chunk c at c ^ (q&7)
    const int tid = threadIdx.x, lane = tid & 63, w = tid >> 6;
    const int l15 = lane & 15, l4 = lane >> 4;
    const int flat = blockIdx.x;
    const int qt = 31 - (flat >> 6);
    const int bh = flat & 63;
    const int b = bh >> 4, h = bh & 15;
    const int qb = qt * 64;

    // Q fragments: rows w*16 + l15, dh = kk*32 + l4*8 .. +7
    bf16x8 qf[4];
    {
        const size_t rowQ = (size_t)(b * 2048 + qb + w * 16 + l15) * 4096 + h * 128;
#pragma unroll
        for (int kk = 0; kk < 4; kk++)
            qf[kk] = *reinterpret_cast<const bf16x8*>(&qk[rowQ + kk * 32 + l4 * 8]);
    }

    // staging geometry (per pass of 256 threads x 16B):
    const int krow_i = tid >> 4, kslot = tid & 15;   // K: 16 rows/pass, 16 chunks/row
    const int vrow_i = tid >> 3, vslot = tid & 7;    // V: 32 rows/pass, 8 chunks/row

    float m_r[4], l_r[4];
    f32x4 o[8] = {};
#pragma unroll
    for (int j = 0; j < 4; ++j) { m_r[j] = -1e30f; l_r[j] = 0.f; }

    for (int kt = 0; kt <= qt; ++kt) {
        const int kvb = kt * 64;
        // ---- stage K [64][128] and V^T [128][64] via global_load_lds ----
#pragma unroll
        for (int p = 0; p < 4; ++p) {
            const int rowk = p * 16 + krow_i;
            const int ck = kslot ^ (rowk & 15);
            __builtin_amdgcn_global_load_lds(
                (gbl_void*)(qk + (size_t)(b * 2048 + kvb + rowk) * 4096 + 2048 + h * 128 + ck * 8),
                (lds_void*)((char*)Ks + p * 4096 + w * 1024), 16, 0, 0);
        }
#pragma unroll
        for (int p = 0; p < 4; ++p) {
            const int rowv = p * 32 + vrow_i;
            const int cv = vslot ^ (rowv & 7);
            __builtin_amdgcn_global_load_lds(
                (gbl_void*)(vt + (size_t)(h * 128 + rowv) * 8192 + b * 2048 + kvb + cv * 8),
                (lds_void*)((char*)Vs + p * 4096 + w * 1024), 16, 0, 0);
        }
        __syncthreads();

        // ---- scores: S[16q][64kv] per wave ----
        f32x4 s[4] = {};
#pragma unroll
        for (int cb = 0; cb < 4; ++cb) {
            const int krow = cb * 16 + l15;
#pragma unroll
            for (int kk = 0; kk < 4; ++kk) {
                bf16x8 kf = *reinterpret_cast<const bf16x8*>(
                    &Ks[krow * 128 + (((kk * 4 + l4) ^ (krow & 15)) << 3)]);
                s[cb] = __builtin_amdgcn_mfma_f32_16x16x32_bf16(qf[kk], kf, s[cb], 0, 0, 0);
            }
        }
        const float sc = 0.08838834764831845f;  // 1/sqrt(128)
#pragma unroll
        for (int cb = 0; cb < 4; ++cb) s[cb] *= sc;

        if (kt == qt) {  // diagonal mask
#pragma unroll
            for (int cb = 0; cb < 4; ++cb)
#pragma unroll
                for (int j = 0; j < 4; ++j) {
                    int lr = w * 16 + l4 * 4 + j, lc = cb * 16 + l15;
                    if (lc > lr) s[cb][j] = -1e30f;
                }
        }

        // ---- online softmax ----
#pragma unroll
        for (int j = 0; j < 4; ++j) {
            float tm = fmaxf(fmaxf(s[0][j], s[1][j]), fmaxf(s[2][j], s[3][j]));
#pragma unroll
            for (int msk = 1; msk < 16; msk <<= 1)
                tm = fmaxf(tm, __shfl_xor(tm, msk, 64));
            float mnew = fmaxf(m_r[j], tm);
            float alpha = __expf(m_r[j] - mnew);
            m_r[j] = mnew;
            float rs = 0.f;
#pragma unroll
            for (int cb = 0; cb < 4; ++cb) {
                float p = __expf(s[cb][j] - mnew);
                s[cb][j] = p;
                rs += p;
            }
#pragma unroll
            for (int msk = 1; msk < 16; msk <<= 1)
                rs += __shfl_xor(rs, msk, 64);
            l_r[j] = l_r[j] * alpha + rs;
#pragma unroll
            for (int d = 0; d < 8; ++d) o[d][j] *= alpha;
        }

        // ---- P -> LDS (bf16, swizzled, wave-private; no barrier needed) ----
#pragma unroll
        for (int cb = 0; cb < 4; ++cb)
#pragma unroll
            for (int j = 0; j < 4; ++j) {
                const int r = l4 * 4 + j;
                const int e = cb * 16 + l15;
                Ps[w * 1024 + r * 64 + (((e >> 3) ^ (r & 7)) << 3) + (e & 7)] = f2bf(s[cb][j]);
            }

        // ---- PV: O += P @ V ----
#pragma unroll
        for (int ks = 0; ks < 2; ++ks) {
            bf16x8 pf = *reinterpret_cast<const bf16x8*>(
                &Ps[w * 1024 + l15 * 64 + (((ks * 4 + l4) ^ (l15 & 7)) << 3)]);
#pragma unroll
            for (int d = 0; d < 8; ++d) {
                const int dr = d * 16 + l15;
                bf16x8 vf = *reinterpret_cast<const bf16x8*>(
                    &Vs[dr * 64 + (((ks * 4 + l4) ^ (dr & 7)) << 3)]);
                o[d] = __builtin_amdgcn_mfma_f32_16x16x32_bf16(pf, vf, o[d], 0, 0, 0);
            }
        }
        __syncthreads();
    }

    // ---- epilogue ----
#pragma unroll
    for (int j = 0; j < 4; ++j) {
        float inv = 1.0f / l_r[j];
        size_t row = (size_t)(b * 2048 + qb + w * 16 + l4 * 4 + j) * 2048 + h * 128;
#pragma unroll
        for (int d = 0; d < 8; ++d)
            ctx[row + d * 16 + l15] = f2bf(o[d][j] * inv);
    }
}

extern "C" void kernel_launch(void* const* d_in, const int* in_sizes, int n_in,
                              void* d_out, int out_size, void* d_ws, size_t ws_size,
                              hipStream_t stream) {
    const float* x  = (const float*)d_in[0];
    const float* Wq = (const float*)d_in[1];
    const float* Wk = (const float*)d_in[2];
    const float* Wv = (const float*)d_in[3];
    const float* Wo = (const float*)d_in[4];
    const float* bo = (const float*)d_in[5];
    float* out = (float*)d_out;

    char* ws = (char*)d_ws;
    u16* xb  = (u16*)(ws);                         // 8192x2048 bf16 (33.5MB); reused as ctx
    u16* wt  = (u16*)(ws + 33554432);              // WqT|WkT|WvT, 3x 2048x2048 bf16 (25.2MB)
    u16* wto = (u16*)(ws + 33554432 + 25165824);   // WoT 2048x2048 bf16 (8.4MB)
    u16* qk  = (u16*)(ws + 67108864);              // 8192x4096 bf16 (67.1MB)
    u16* vtb = (u16*)(ws + 134217728);             // 2048x8192 bf16 V^T (33.5MB)
    u16* wtv = wt + 2 * 2048 * 2048;
    u16* ctxb = xb;

    cvt_bf16_kernel<<<16384, 256, 0, stream>>>(x, xb, 4194304);
    dim3 tb(32, 8), tg(64, 64);
    transpose_w_kernel<<<tg, tb, 0, stream>>>(Wq, wt);
    transpose_w_kernel<<<tg, tb, 0, stream>>>(Wk, wt + 2048 * 2048);
    transpose_w_kernel<<<tg, tb, 0, stream>>>(Wv, wtv);
    transpose_w_kernel<<<tg, tb, 0, stream>>>(Wo, wto);

    // Q|K: [8192][4096] = xb @ [WqT|WkT]^T
    gemm_bt_kernel<false><<<dim3(64, 32), 256, 0, stream>>>(xb, wt, qk, nullptr, 8192, 4096, 2048);
    // V^T: [2048][8192] = WvT @ xb^T
    gemm_bt_kernel<false><<<dim3(16, 64), 256, 0, stream>>>(wtv, xb, vtb, nullptr, 2048, 8192, 2048);
    attn_kernel<<<2048, 256, 0, stream>>>(qk, vtb, ctxb);
    gemm_bt_kernel<true><<<dim3(64, 16), 256, 0, stream>>>(ctxb, wto, out, bo, 8192, 2048, 2048);
}

// Round 4
// 590.228 us; speedup vs baseline: 1.4101x; 1.0178x over previous
//
#include <hip/hip_runtime.h>
#include <stdint.h>

typedef unsigned short u16;
typedef __attribute__((ext_vector_type(4))) float f32x4;
typedef __attribute__((ext_vector_type(8))) __bf16 bf16x8;
typedef __attribute__((address_space(3))) void lds_void;
typedef const __attribute__((address_space(1))) void gbl_void;

__device__ __forceinline__ u16 f2bf(float f) {
    uint32_t u = __float_as_uint(f);
    u += 0x7FFFu + ((u >> 16) & 1u);
    return (u16)(u >> 16);
}

// ---------------- x f32 -> bf16 ----------------
__global__ __launch_bounds__(256) void cvt_bf16_kernel(const float* __restrict__ in,
                                                       u16* __restrict__ out, int n4) {
    int i = blockIdx.x * 256 + threadIdx.x;
    if (i >= n4) return;
    float4 v = reinterpret_cast<const float4*>(in)[i];
    ushort4 o;
    o.x = f2bf(v.x); o.y = f2bf(v.y); o.z = f2bf(v.z); o.w = f2bf(v.w);
    reinterpret_cast<ushort4*>(out)[i] = o;
}

// ---------------- W [K][N] f32 -> Wt [N][K] bf16 (2048x2048) ----------------
__global__ __launch_bounds__(256) void transpose_w_kernel(const float* __restrict__ W,
                                                          u16* __restrict__ Wt) {
    __shared__ float tile[32][33];
    const int bx = blockIdx.x, by = blockIdx.y;
    const int tx = threadIdx.x;  // 0..31
    const int ty = threadIdx.y;  // 0..7
#pragma unroll
    for (int i = 0; i < 4; i++)
        tile[ty + i * 8][tx] = W[(size_t)(by * 32 + ty + i * 8) * 2048 + bx * 32 + tx];
    __syncthreads();
#pragma unroll
    for (int i = 0; i < 4; i++)
        Wt[(size_t)(bx * 32 + ty + i * 8) * 2048 + by * 32 + tx] = f2bf(tile[tx][ty + i * 8]);
}

// ---------------- GEMM: C[M][N] = A[M][K] * Bt[N][K]^T  (bf16 in) ----------------
// 128x128 tile, 4 waves, BK=32. 3-slot LDS ring, prefetch distance 2,
// counted vmcnt + raw barriers (T4), XCD-bijective block swizzle (T1/m204).
template <bool F32OUT>
__global__ __launch_bounds__(256) void gemm_bt_kernel(const u16* __restrict__ A,
                                                      const u16* __restrict__ Bt,
                                                      void* __restrict__ Cout,
                                                      const float* __restrict__ bias,
                                                      int M, int N, int K) {
    __shared__ u16 As[3 * 4096];  // 3 slots x [128][32]
    __shared__ u16 Bs[3 * 4096];
    const int tid = threadIdx.x;
    const int lane = tid & 63, wave = tid >> 6;
    const int l15 = lane & 15, l4 = lane >> 4;
    const int wm = wave >> 1, wn = wave & 1;

    // XCD-aware bijective remap (m204): contiguous wgid chunk per XCD.
    const int gx = gridDim.x;
    const int nwg = gx * gridDim.y;
    const int flat0 = blockIdx.y * gx + blockIdx.x;
    const int q = nwg >> 3, r = nwg & 7;
    const int xcd = flat0 & 7, idx = flat0 >> 3;
    const int wgid = (xcd < r ? xcd * (q + 1) : r * (q + 1) + (xcd - r) * q) + idx;
    const int bm = wgid % gx, bn = wgid / gx;

    f32x4 acc[4][4] = {};

    const int r0 = tid >> 2;
    const int r1 = r0 + 64;
    const int c0 = (tid & 3) * 8;
    const u16* ga0 = A + (size_t)(bm * 128 + r0) * K + c0;
    const u16* ga1 = A + (size_t)(bm * 128 + r1) * K + c0;
    const u16* gb0 = Bt + (size_t)(bn * 128 + r0) * K + c0;
    const u16* gb1 = Bt + (size_t)(bn * 128 + r1) * K + c0;
    const int woff = wave * 1024;  // bytes within slot

#define STAGE_TILE(T, SLOT)                                                              \
    {                                                                                    \
        const int kb_ = (T) << 5;                                                        \
        const int sb_ = (SLOT) * 8192;                                                   \
        __builtin_amdgcn_global_load_lds((gbl_void*)(ga0 + kb_),                         \
                                         (lds_void*)((char*)As + sb_ + woff), 16, 0, 0); \
        __builtin_amdgcn_global_load_lds((gbl_void*)(ga1 + kb_),                         \
                                         (lds_void*)((char*)As + sb_ + 4096 + woff), 16, 0, 0); \
        __builtin_amdgcn_global_load_lds((gbl_void*)(gb0 + kb_),                         \
                                         (lds_void*)((char*)Bs + sb_ + woff), 16, 0, 0); \
        __builtin_amdgcn_global_load_lds((gbl_void*)(gb1 + kb_),                         \
                                         (lds_void*)((char*)Bs + sb_ + 4096 + woff), 16, 0, 0); \
    }

    const int nt = K >> 5;
    // prologue: tiles 0,1 into slots 0,1
    STAGE_TILE(0, 0);
    STAGE_TILE(1, 1);

    int cs = 0, ps = 2;  // slot of tile t, slot of tile t+2
    for (int t = 0; t < nt; ++t) {
        if (t + 2 < nt) {
            STAGE_TILE(t + 2, ps);
            asm volatile("s_waitcnt vmcnt(8)" ::: "memory");
        } else if (t + 2 == nt) {
            asm volatile("s_waitcnt vmcnt(4)" ::: "memory");
        } else {
            asm volatile("s_waitcnt vmcnt(0)" ::: "memory");
        }
        __builtin_amdgcn_s_barrier();
        __builtin_amdgcn_sched_barrier(0);  // pin reads below the barrier

        const u16* as = As + cs * 4096;
        const u16* bs = Bs + cs * 4096;
        bf16x8 af[4], bfr[4];
#pragma unroll
        for (int m = 0; m < 4; ++m)
            af[m] = *reinterpret_cast<const bf16x8*>(&as[(wm * 64 + m * 16 + l15) * 32 + l4 * 8]);
#pragma unroll
        for (int n = 0; n < 4; ++n)
            bfr[n] = *reinterpret_cast<const bf16x8*>(&bs[(wn * 64 + n * 16 + l15) * 32 + l4 * 8]);
#pragma unroll
        for (int m = 0; m < 4; ++m)
#pragma unroll
            for (int n = 0; n < 4; ++n)
                acc[m][n] = __builtin_amdgcn_mfma_f32_16x16x32_bf16(af[m], bfr[n], acc[m][n], 0, 0, 0);

        __builtin_amdgcn_s_barrier();       // reads done before next iter's stage overwrites
        __builtin_amdgcn_sched_barrier(0);  // pin next stage below this barrier
        cs = (cs == 2) ? 0 : cs + 1;
        ps = (ps == 2) ? 0 : ps + 1;
    }
#undef STAGE_TILE

    const int rbase = bm * 128 + wm * 64;
    const int cbase = bn * 128 + wn * 64;
#pragma unroll
    for (int m = 0; m < 4; ++m) {
#pragma unroll
        for (int n = 0; n < 4; ++n) {
            const int c = cbase + n * 16 + l15;
#pragma unroll
            for (int j = 0; j < 4; ++j) {
                const int rr = rbase + m * 16 + l4 * 4 + j;
                if (F32OUT)
                    ((float*)Cout)[(size_t)rr * N + c] = acc[m][n][j] + bias[c];
                else
                    ((u16*)Cout)[(size_t)rr * N + c] = f2bf(acc[m][n][j]);
            }
        }
    }
}

// ---------------- causal flash attention ----------------
// grid: 2048 1-D, heavy-first: qt = 31 - flat/64, bh = flat%64.
// qk: [B*S][4096] bf16 (q | k, head-major 16x128). vt: [2048=h*128+dh][8192=b*2048+s].
// ctx: [B*S][2048] bf16.
// LDS tiles linear (global_load_lds), source pre-swizzled; reads apply same XOR.
__global__ __launch_bounds__(256) void attn_kernel(const u16* __restrict__ qk,
                                                   const u16* __restrict__ vt,
                                                   u16* __restrict__ ctx) {
    __shared__ u16 Ks[64 * 128];     // [kv][dh], 16B chunk c stored at c ^ (kv&15)
    __shared__ u16 Vs[128 * 64];     // [dh][kv], 16B chunk c stored at c ^ (dh&7)
    __shared__ u16 Ps[4 * 16 * 64];  // per-wave [q][kv], chunk c at c ^ (q&7)
    const int tid = threadIdx.x, lane = tid & 63, w = tid >> 6;
    const int l15 = lane & 15, l4 = lane >> 4;
    const int flat = blockIdx.x;
    const int qt = 31 - (flat >> 6);
    const int bh = flat & 63;
    const int b = bh >> 4, h = bh & 15;
    const int qb = qt * 64;

    bf16x8 qf[4];
    {
        const size_t rowQ = (size_t)(b * 2048 + qb + w * 16 + l15) * 4096 + h * 128;
#pragma unroll
        for (int kk = 0; kk < 4; kk++)
            qf[kk] = *reinterpret_cast<const bf16x8*>(&qk[rowQ + kk * 32 + l4 * 8]);
    }

    const int krow_i = tid >> 4, kslot = tid & 15;
    const int vrow_i = tid >> 3, vslot = tid & 7;

    float m_r[4], l_r[4];
    f32x4 o[8] = {};
#pragma unroll
    for (int j = 0; j < 4; ++j) { m_r[j] = -1e30f; l_r[j] = 0.f; }

    for (int kt = 0; kt <= qt; ++kt) {
        const int kvb = kt * 64;
#pragma unroll
        for (int p = 0; p < 4; ++p) {
            const int rowk = p * 16 + krow_i;
            const int ck = kslot ^ (rowk & 15);
            __builtin_amdgcn_global_load_lds(
                (gbl_void*)(qk + (size_t)(b * 2048 + kvb + rowk) * 4096 + 2048 + h * 128 + ck * 8),
                (lds_void*)((char*)Ks + p * 4096 + w * 1024), 16, 0, 0);
        }
#pragma unroll
        for (int p = 0; p < 4; ++p) {
            const int rowv = p * 32 + vrow_i;
            const int cv = vslot ^ (rowv & 7);
            __builtin_amdgcn_global_load_lds(
                (gbl_void*)(vt + (size_t)(h * 128 + rowv) * 8192 + b * 2048 + kvb + cv * 8),
                (lds_void*)((char*)Vs + p * 4096 + w * 1024), 16, 0, 0);
        }
        __syncthreads();

        f32x4 s[4] = {};
#pragma unroll
        for (int cb = 0; cb < 4; ++cb) {
            const int krow = cb * 16 + l15;
#pragma unroll
            for (int kk = 0; kk < 4; ++kk) {
                bf16x8 kf = *reinterpret_cast<const bf16x8*>(
                    &Ks[krow * 128 + (((kk * 4 + l4) ^ (krow & 15)) << 3)]);
                s[cb] = __builtin_amdgcn_mfma_f32_16x16x32_bf16(qf[kk], kf, s[cb], 0, 0, 0);
            }
        }
        const float sc = 0.08838834764831845f;  // 1/sqrt(128)
#pragma unroll
        for (int cb = 0; cb < 4; ++cb) s[cb] *= sc;

        if (kt == qt) {
#pragma unroll
            for (int cb = 0; cb < 4; ++cb)
#pragma unroll
                for (int j = 0; j < 4; ++j) {
                    int lr = w * 16 + l4 * 4 + j, lc = cb * 16 + l15;
                    if (lc > lr) s[cb][j] = -1e30f;
                }
        }

#pragma unroll
        for (int j = 0; j < 4; ++j) {
            float tm = fmaxf(fmaxf(s[0][j], s[1][j]), fmaxf(s[2][j], s[3][j]));
#pragma unroll
            for (int msk = 1; msk < 16; msk <<= 1)
                tm = fmaxf(tm, __shfl_xor(tm, msk, 64));
            float mnew = fmaxf(m_r[j], tm);
            float alpha = __expf(m_r[j] - mnew);
            m_r[j] = mnew;
            float rs = 0.f;
#pragma unroll
            for (int cb = 0; cb < 4; ++cb) {
                float p = __expf(s[cb][j] - mnew);
                s[cb][j] = p;
                rs += p;
            }
#pragma unroll
            for (int msk = 1; msk < 16; msk <<= 1)
                rs += __shfl_xor(rs, msk, 64);
            l_r[j] = l_r[j] * alpha + rs;
#pragma unroll
            for (int d = 0; d < 8; ++d) o[d][j] *= alpha;
        }

#pragma unroll
        for (int cb = 0; cb < 4; ++cb)
#pragma unroll
            for (int j = 0; j < 4; ++j) {
                const int rr = l4 * 4 + j;
                const int e = cb * 16 + l15;
                Ps[w * 1024 + rr * 64 + (((e >> 3) ^ (rr & 7)) << 3) + (e & 7)] = f2bf(s[cb][j]);
            }

#pragma unroll
        for (int ks = 0; ks < 2; ++ks) {
            bf16x8 pf = *reinterpret_cast<const bf16x8*>(
                &Ps[w * 1024 + l15 * 64 + (((ks * 4 + l4) ^ (l15 & 7)) << 3)]);
#pragma unroll
            for (int d = 0; d < 8; ++d) {
                const int dr = d * 16 + l15;
                bf16x8 vf = *reinterpret_cast<const bf16x8*>(
                    &Vs[dr * 64 + (((ks * 4 + l4) ^ (dr & 7)) << 3)]);
                o[d] = __builtin_amdgcn_mfma_f32_16x16x32_bf16(pf, vf, o[d], 0, 0, 0);
            }
        }
        __syncthreads();
    }

#pragma unroll
    for (int j = 0; j < 4; ++j) {
        float inv = 1.0f / l_r[j];
        size_t row = (size_t)(b * 2048 + qb + w * 16 + l4 * 4 + j) * 2048 + h * 128;
#pragma unroll
        for (int d = 0; d < 8; ++d)
            ctx[row + d * 16 + l15] = f2bf(o[d][j] * inv);
    }
}

extern "C" void kernel_launch(void* const* d_in, const int* in_sizes, int n_in,
                              void* d_out, int out_size, void* d_ws, size_t ws_size,
                              hipStream_t stream) {
    const float* x  = (const float*)d_in[0];
    const float* Wq = (const float*)d_in[1];
    const float* Wk = (const float*)d_in[2];
    const float* Wv = (const float*)d_in[3];
    const float* Wo = (const float*)d_in[4];
    const float* bo = (const float*)d_in[5];
    float* out = (float*)d_out;

    char* ws = (char*)d_ws;
    u16* xb  = (u16*)(ws);                         // 8192x2048 bf16 (33.5MB); reused as ctx
    u16* wt  = (u16*)(ws + 33554432);              // WqT|WkT|WvT, 3x 2048x2048 bf16 (25.2MB)
    u16* wto = (u16*)(ws + 33554432 + 25165824);   // WoT 2048x2048 bf16 (8.4MB)
    u16* qk  = (u16*)(ws + 67108864);              // 8192x4096 bf16 (67.1MB)
    u16* vtb = (u16*)(ws + 134217728);             // 2048x8192 bf16 V^T (33.5MB)
    u16* wtv = wt + 2 * 2048 * 2048;
    u16* ctxb = xb;

    cvt_bf16_kernel<<<16384, 256, 0, stream>>>(x, xb, 4194304);
    dim3 tb(32, 8), tg(64, 64);
    transpose_w_kernel<<<tg, tb, 0, stream>>>(Wq, wt);
    transpose_w_kernel<<<tg, tb, 0, stream>>>(Wk, wt + 2048 * 2048);
    transpose_w_kernel<<<tg, tb, 0, stream>>>(Wv, wtv);
    transpose_w_kernel<<<tg, tb, 0, stream>>>(Wo, wto);

    // Q|K: [8192][4096] = xb @ [WqT|WkT]^T
    gemm_bt_kernel<false><<<dim3(64, 32), 256, 0, stream>>>(xb, wt, qk, nullptr, 8192, 4096, 2048);
    // V^T: [2048][8192] = WvT @ xb^T
    gemm_bt_kernel<false><<<dim3(16, 64), 256, 0, stream>>>(wtv, xb, vtb, nullptr, 2048, 8192, 2048);
    attn_kernel<<<2048, 256, 0, stream>>>(qk, vtb, ctxb);
    gemm_bt_kernel<true><<<dim3(64, 16), 256, 0, stream>>>(ctxb, wto, out, bo, 8192, 2048, 2048);
}